// Round 4
// baseline (322.481 us; speedup 1.0000x reference)
//
#include <hip/hip_runtime.h>
#include <hip/hip_bf16.h>
#include <stdint.h>

typedef __bf16 bf16_t;
typedef bf16_t bf16x8 __attribute__((ext_vector_type(8)));
typedef bf16_t bf16x4 __attribute__((ext_vector_type(4)));
typedef float f32x4 __attribute__((ext_vector_type(4)));

#define BATCH 16
#define HH    56
#define DIMK  384
#define M_TOT (BATCH*HH*HH)   // 50176
#define SCALE 0.17677669529663687f

__device__ __forceinline__ void async_load16(const bf16_t* g, const bf16_t* l) {
  __builtin_amdgcn_global_load_lds((const __attribute__((address_space(1))) void*)g,
                                   (__attribute__((address_space(3))) void*)l,
                                   16, 0, 0);
}

// DPP rotate within 16-lane row (VALU pipe — keeps softmax off the LDS pipe)
template<int CTRL>
__device__ __forceinline__ float dpp_ror(float x) {
  return __int_as_float(__builtin_amdgcn_mov_dpp(__float_as_int(x), CTRL, 0xf, 0xf, false));
}
__device__ __forceinline__ float rowmax16(float v) {
  v = fmaxf(v, dpp_ror<0x121>(v));  // row_ror:1
  v = fmaxf(v, dpp_ror<0x122>(v));  // row_ror:2
  v = fmaxf(v, dpp_ror<0x124>(v));  // row_ror:4
  v = fmaxf(v, dpp_ror<0x128>(v));  // row_ror:8
  return v;
}
__device__ __forceinline__ float rowsum16(float v) {
  v += dpp_ror<0x121>(v);
  v += dpp_ror<0x122>(v);
  v += dpp_ror<0x124>(v);
  v += dpp_ror<0x128>(v);
  return v;
}

// ---------------------------------------------------------------------------
__global__ void k_zero(float* __restrict__ p, int n) {
  int i = blockIdx.x * 256 + threadIdx.x;
  if (i < n) p[i] = 0.f;
}

// transpose w_qkv [384][1152] fp32 -> wT [1152][384] bf16
__global__ void k_transpose(const float* __restrict__ w, bf16_t* __restrict__ wT) {
  int idx = blockIdx.x * 256 + threadIdx.x;
  if (idx >= 1152 * 384) return;
  int n = idx / 384, k = idx - n * 384;
  wT[idx] = (bf16_t)w[k * 1152 + n];
}

// wcombT[n][k] = sum_j w_out[k][j] * w_post[j][n]; bcomb[n] = b_out@w_post + b_post
__global__ void k_comb(const float* __restrict__ w_out, const float* __restrict__ b_out,
                       const float* __restrict__ w_post, const float* __restrict__ b_post,
                       bf16_t* __restrict__ wcombT, float* __restrict__ bcomb) {
  __shared__ float col[384];
  const int n = blockIdx.x, t = threadIdx.x;
  for (int j = t; j < 384; j += 256) col[j] = w_post[j * 384 + n];
  __syncthreads();
  for (int k = t; k < 384; k += 256) {
    float acc = 0.f;
    for (int j = 0; j < 384; ++j) acc += w_out[k * 384 + j] * col[j];
    wcombT[n * 384 + k] = (bf16_t)acc;
  }
  if (t == 0) {
    float acc = b_post[n];
    for (int j = 0; j < 384; ++j) acc += b_out[j] * col[j];
    bcomb[n] = acc;
  }
}

// bias/mask init table in MFMA C-layout, pre-divided by SCALE.
// layout: [cls 0..3][tile=mt*4+nt][lane][reg] fp32  (64 KB)
__global__ void k_bias(const float* __restrict__ pos, float* __restrict__ biasC) {
  int idx = blockIdx.x * 256 + threadIdx.x;
  if (idx >= 4 * 16 * 64 * 4) return;
  int reg = idx & 3, lane = (idx >> 2) & 63, tile = (idx >> 8) & 15, cls = idx >> 12;
  int mt = tile >> 2, nt = tile & 3, lc = lane & 15, quad = lane >> 4;
  int m = mt * 16 + quad * 4 + reg, n = nt * 16 + lc;
  float v = -1e32f;
  if (m < 49 && n < 49) {
    int ty = m / 7, tx = m % 7, jy = n / 7, jx = n % 7;
    bool dead = ((cls & 1) && ((m >= 28) != (n >= 28))) ||
                ((cls & 2) && ((tx >= 4) != (jx >= 4)));
    v = dead ? -1e32f : pos[(jy - ty + 6) * 13 + (jx - tx + 6)] * (1.0f / SCALE);
  }
  biasC[idx] = v;
}

// x fp32 -> bf16 with roll(-3,-3) fused.  xb lives in d_out (dead scratch).
// 8 elems/thread: 2x f32x4 load -> 1x bf16x8 (16B) store.
__global__ void k_convroll(const float* __restrict__ x, bf16_t* __restrict__ xb) {
  int idx = blockIdx.x * 256 + threadIdx.x;
  if (idx >= M_TOT * 48) return;
  int row = idx / 48, c = idx - row * 48;
  int bb = row / 3136, rem = row - bb * 3136, i = rem / 56, j = rem - i * 56;
  int si = i + 3; if (si >= 56) si -= 56;
  int sj = j + 3; if (sj >= 56) sj -= 56;
  const float* src = x + ((size_t)(bb * 3136 + si * 56 + sj)) * 384 + c * 8;
  f32x4 v0 = *(const f32x4*)src;
  f32x4 v1 = *(const f32x4*)(src + 4);
  bf16x8 o;
#pragma unroll
  for (int u = 0; u < 4; ++u) { o[u] = (bf16_t)v0[u]; o[4 + u] = (bf16_t)v1[u]; }
  *(bf16x8*)(xb + (size_t)row * 384 + c * 8) = o;
}

// ---------------------------------------------------------------------------
// GEMM: C[M x N] = A[M x K(lda)] * B^T[N x K], 128x128 tile, BK=32,
// 4-buffer depth-2 prefetch with COUNTED vmcnt (T4): loads stay in flight
// across raw s_barriers; each wave certifies its own stage(kt) retired via
// s_waitcnt vmcnt(8) BEFORE the barrier, so after the barrier all waves'
// stage(kt) writes have landed (race-free idiom from the 8-phase template).
// WAR safety: stage(kt+2) overwrites the buffer read at iter kt-2, whose
// ds_reads retired before barrier(kt-1); the write is issued after
// barrier(kt-1) -> one full barrier of separation (needs 4 buffers, not 3).
// Tail iters use vmcnt(4)/vmcnt(0) (blanket vmcnt(8) would be a no-op there).
// LDS swizzle (T2 via m173): linear LDS dest, global source chunk permuted
// kc ^ ((r>>1)&3), fragment reads apply the same XOR -> 2-way residual (free).
// XCD-chunk bijective swizzle (T1). MODE 1: fp32 C + roll(+3,+3) + bias.
template<int MODE>
__global__ __launch_bounds__(256)
void k_gemm(const bf16_t* __restrict__ A, const bf16_t* __restrict__ B,
            void* __restrict__ Cv, const float* __restrict__ bias,
            int Ndim, int Kdim, int lda) {
  __shared__ __align__(16) bf16_t As[4][128 * 32];   // 4 x 8 KB
  __shared__ __align__(16) bf16_t Bs[4][128 * 32];   // 4 x 8 KB  (64 KB total)
  const int tid  = threadIdx.x;
  const int wave = tid >> 6;
  const int lane = tid & 63;
  const int wr = wave >> 1, wc = wave & 1;

  const int gx   = gridDim.x;
  const int nwg  = gx * gridDim.y;
  const int flat = blockIdx.y * gx + blockIdx.x;
  const int qch  = nwg >> 3;                      // tiles per XCD (nwg % 8 == 0)
  const int nf   = (flat & 7) * qch + (flat >> 3);
  const int bx   = nf % gx;
  const int by   = nf / gx;

  const int row0 = by * 128;
  const int col0 = bx * 128;

  // staging map: 512 16B-chunks per matrix per K-step (128 rows x 4 chunks),
  // 2 rounds of 256 threads. LDS slot (r,kc) receives GLOBAL chunk
  // (r, kc ^ ((r>>1)&3)).
  const bf16_t* aptr[2];
  const bf16_t* bptr[2];
  int dst[2];
#pragma unroll
  for (int c = 0; c < 2; ++c) {
    int linear = c * 256 + tid;
    int r  = linear >> 2;
    int kc = linear & 3;
    int gk = kc ^ ((r >> 1) & 3);
    dst[c] = linear * 8;                      // element offset in LDS
    aptr[c] = A + (size_t)(row0 + r) * lda + gk * 8;
    bptr[c] = B + (size_t)(col0 + r) * Kdim + gk * 8;
  }

  f32x4 acc[4][4] = {};
  const int lr = lane >> 4;
  const int lc = lane & 15;
  // fragment read offsets: row stride 32 elem (64B); k-chunk lr, swizzled
  // sc = lr ^ ((row>>1)&3); row bits 0..3 == lc here.
  unsigned aoff[4], boff[4];
  const int scx = lr ^ ((lc >> 1) & 3);
#pragma unroll
  for (int mi = 0; mi < 4; ++mi) aoff[mi] = (unsigned)((wr * 64 + mi * 16 + lc) * 32 + scx * 8);
#pragma unroll
  for (int ni = 0; ni < 4; ++ni) boff[ni] = (unsigned)((wc * 64 + ni * 16 + lc) * 32 + scx * 8);

  const int kiters = Kdim >> 5;   // 12

  // prologue: stage K-steps 0 and 1 (4 gload_lds each)
#pragma unroll
  for (int c = 0; c < 2; ++c) {
    async_load16(aptr[c], As[0] + dst[c]);
    async_load16(bptr[c], Bs[0] + dst[c]);
  }
#pragma unroll
  for (int c = 0; c < 2; ++c) {
    async_load16(aptr[c] + 32, As[1] + dst[c]);
    async_load16(bptr[c] + 32, Bs[1] + dst[c]);
  }

  for (int kt = 0; kt < kiters; ++kt) {
    const int cur = kt & 3;
    if (kt + 2 < kiters) {
      const int koff = (kt + 2) * 32;
      const int nb = (kt + 2) & 3;
#pragma unroll
      for (int c = 0; c < 2; ++c) {
        async_load16(aptr[c] + koff, As[nb] + dst[c]);
        async_load16(bptr[c] + koff, Bs[nb] + dst[c]);
      }
      asm volatile("s_waitcnt vmcnt(8)" ::: "memory");   // own stage(kt) retired
    } else if (kt + 2 == kiters) {
      asm volatile("s_waitcnt vmcnt(4)" ::: "memory");   // 8 outstanding -> 4
    } else {
      asm volatile("s_waitcnt vmcnt(0)" ::: "memory");   // last iter
    }
    asm volatile("s_barrier" ::: "memory");              // all waves' stage(kt) landed

    bf16x8 af[4], bfr[4];
#pragma unroll
    for (int mi = 0; mi < 4; ++mi) af[mi]  = *(const bf16x8*)(As[cur] + aoff[mi]);
#pragma unroll
    for (int ni = 0; ni < 4; ++ni) bfr[ni] = *(const bf16x8*)(Bs[cur] + boff[ni]);
#pragma unroll
    for (int mi = 0; mi < 4; ++mi)
#pragma unroll
      for (int ni = 0; ni < 4; ++ni)
        acc[mi][ni] = __builtin_amdgcn_mfma_f32_16x16x32_bf16(af[mi], bfr[ni], acc[mi][ni], 0, 0, 0);
  }

  // Epilogue: C/D layout col=lane&15, row=quad*4+reg (verified m89/m91)
#pragma unroll
  for (int mi = 0; mi < 4; ++mi) {
#pragma unroll
    for (int rr = 0; rr < 4; ++rr) {
      int grow = row0 + wr * 64 + mi * 16 + lr * 4 + rr;
      size_t orow;
      if (MODE == 1) {
        int bb  = grow / 3136;
        int rem = grow - bb * 3136;
        int i = rem / 56;
        int j = rem - i * 56;
        int si = i + 3; if (si >= 56) si -= 56;
        int sj = j + 3; if (sj >= 56) sj -= 56;
        orow = (size_t)(bb * 3136 + si * 56 + sj);   // fused roll(+3,+3)
      } else {
        orow = (size_t)grow;
      }
#pragma unroll
      for (int ni = 0; ni < 4; ++ni) {
        int gcol = col0 + wc * 64 + ni * 16 + lc;
        float v = acc[mi][ni][rr];
        if (MODE == 1) {
          ((float*)Cv)[orow * (size_t)Ndim + gcol] = v + bias[gcol];
        } else {
          ((bf16_t*)Cv)[orow * (size_t)Ndim + gcol] = (bf16_t)v;
        }
      }
    }
  }
}

// ---------------------------------------------------------------------------
// MFMA attention: one wave per (b, head, window); 4 waves/block.
// 49 tokens padded to 64. Q/K/V fragments loaded directly from global
// (per-lane row addresses, clamp row 48 for pads). Bias+mask pre-baked in
// C-layout (biasC). Softmax reduce via DPP row_ror. P via LDS (stride 72).
// Output written in place into the q slot of qkv.
__global__ __launch_bounds__(256)
void k_attn(const float* __restrict__ biasC, bf16_t* __restrict__ qkv) {
  __shared__ __align__(16) bf16_t Ps[4 * 64 * 72];   // 36864 B
  const int tid = threadIdx.x, wid = tid >> 6, lane = tid & 63;
  const int p = blockIdx.x * 4 + wid;                 // 12288 problems
  const int b = p / 768, rem = p - b * 768;
  const int head = rem >> 6, w = rem & 63;
  const int wy = w >> 3, wx = w & 7;
  const int cls = ((wy == 7) ? 1 : 0) | ((wx == 7) ? 2 : 0);
  const int lc = lane & 15, quad = lane >> 4;
  const size_t wbase = ((size_t)b * 3136 + (size_t)wy * 7 * 56 + (size_t)wx * 7) * 1152
                       + head * 32;

  // row offset (elements) for token m within this window
  auto rowoff = [&](int m) -> size_t {
    int ty = m / 7, tx = m - ty * 7;
    return wbase + (size_t)(ty * 56 + tx) * 1152;
  };

  // --- Q (A-frag) and K (B-frag) direct global loads; same rows serve both.
  bf16x8 qf[4], kf[4];
#pragma unroll
  for (int t = 0; t < 4; ++t) {
    int m = t * 16 + lc; if (m > 48) m = 48;
    const bf16_t* r = qkv + rowoff(m);
    qf[t] = *(const bf16x8*)(r + quad * 8);          // Q row m, k-chunk quad
    kf[t] = *(const bf16x8*)(r + 384 + quad * 8);    // K row m (as B-frag col)
  }

  // --- V B-frags: scalar global loads V[n=kc*32+quad*8+u][d=dt*16+lc]
  bf16x8 vf[2][2];
#pragma unroll
  for (int kc = 0; kc < 2; ++kc)
#pragma unroll
    for (int u = 0; u < 8; ++u) {
      int n = kc * 32 + quad * 8 + u; if (n > 48) n = 48;
      const bf16_t* r = qkv + rowoff(n) + 768 + lc;
      vf[kc][0][u] = r[0];
      vf[kc][1][u] = r[16];
    }

  // --- S = Q.K^T with acc initialized to (bias+mask)/SCALE
  f32x4 acc[4][4];
  const float* bp = biasC + cls * 4096 + lane * 4;
#pragma unroll
  for (int mt = 0; mt < 4; ++mt)
#pragma unroll
    for (int nt = 0; nt < 4; ++nt)
      acc[mt][nt] = *(const f32x4*)(bp + (mt * 4 + nt) * 256);
#pragma unroll
  for (int mt = 0; mt < 4; ++mt)
#pragma unroll
    for (int nt = 0; nt < 4; ++nt)
      acc[mt][nt] = __builtin_amdgcn_mfma_f32_16x16x32_bf16(qf[mt], kf[nt], acc[mt][nt], 0, 0, 0);

  // --- softmax over n (row m = mt*16+quad*4+reg; 16 cols/lane-row × 4 nt)
  float l[4][4];
#pragma unroll
  for (int mt = 0; mt < 4; ++mt)
#pragma unroll
    for (int reg = 0; reg < 4; ++reg) {
      float mx = fmaxf(fmaxf(acc[mt][0][reg], acc[mt][1][reg]),
                       fmaxf(acc[mt][2][reg], acc[mt][3][reg]));
      mx = rowmax16(mx);
      float s = 0.f;
#pragma unroll
      for (int nt = 0; nt < 4; ++nt) {
        float pe = __expf((acc[mt][nt][reg] - mx) * SCALE);
        acc[mt][nt][reg] = pe;
        s += pe;
      }
      l[mt][reg] = rowsum16(s);
    }

  // --- P -> LDS (C-layout scatter, stride 72: 16B-aligned rows for b128 reads)
  bf16_t* P = Ps + wid * (64 * 72);
#pragma unroll
  for (int mt = 0; mt < 4; ++mt)
#pragma unroll
    for (int nt = 0; nt < 4; ++nt)
#pragma unroll
      for (int reg = 0; reg < 4; ++reg)
        P[(mt * 16 + quad * 4 + reg) * 72 + nt * 16 + lc] = (bf16_t)acc[mt][nt][reg];

  // --- O = P.V  (A-frag = P rows from LDS; B-frag = vf)
  f32x4 oacc[4][2] = {};
#pragma unroll
  for (int mt = 0; mt < 4; ++mt) {
    bf16x8 pf0 = *(const bf16x8*)(P + (mt * 16 + lc) * 72 + quad * 8);
    bf16x8 pf1 = *(const bf16x8*)(P + (mt * 16 + lc) * 72 + 32 + quad * 8);
#pragma unroll
    for (int dt = 0; dt < 2; ++dt) {
      oacc[mt][dt] = __builtin_amdgcn_mfma_f32_16x16x32_bf16(pf0, vf[0][dt], oacc[mt][dt], 0, 0, 0);
      oacc[mt][dt] = __builtin_amdgcn_mfma_f32_16x16x32_bf16(pf1, vf[1][dt], oacc[mt][dt], 0, 0, 0);
    }
  }

  // --- write O into q slot (rows m<49), folding 1/l
#pragma unroll
  for (int mt = 0; mt < 4; ++mt)
#pragma unroll
    for (int reg = 0; reg < 4; ++reg) {
      int m = mt * 16 + quad * 4 + reg;
      if (m < 49) {
        float rl = __builtin_amdgcn_rcpf(l[mt][reg]);
        bf16_t* r = qkv + rowoff(m);
        r[lc]      = (bf16_t)(oacc[mt][0][reg] * rl);
        r[16 + lc] = (bf16_t)(oacc[mt][1][reg] * rl);
      }
    }
}

// ---------------------------------------------------------------------------
extern "C" void kernel_launch(void* const* d_in, const int* in_sizes, int n_in,
                              void* d_out, int out_size, void* d_ws, size_t ws_size,
                              hipStream_t stream) {
  const float* x      = (const float*)d_in[0];
  const float* w_qkv  = (const float*)d_in[1];
  const float* pos    = (const float*)d_in[2];
  const float* w_out  = (const float*)d_in[3];
  const float* b_out  = (const float*)d_in[4];
  const float* w_post = (const float*)d_in[5];
  const float* b_post = (const float*)d_in[6];
  float* out = (float*)d_out;

  const size_t SZ_QKV  = (size_t)M_TOT * 1152 * 2;   // 115.6 MB
  const size_t SZ_WT   = (size_t)1152 * 384 * 2;
  const size_t SZ_WC   = (size_t)384 * 384 * 2;
  const size_t SZ_BC   = 384 * 4;
  const size_t SZ_BIAS = (size_t)4 * 16 * 64 * 4 * 4;  // 64 KB
  const size_t NEEDED  = SZ_QKV + SZ_WT + SZ_WC + SZ_BC + SZ_BIAS;

  if (ws_size < NEEDED) {
    k_zero<<<(out_size + 255) / 256, 256, 0, stream>>>(out, out_size);
    return;
  }

  char* ws = (char*)d_ws;
  bf16_t* qkv   = (bf16_t*)ws;
  bf16_t* wT    = (bf16_t*)(ws + SZ_QKV);
  bf16_t* wcT   = (bf16_t*)(ws + SZ_QKV + SZ_WT);
  float*  bc    = (float*)(ws + SZ_QKV + SZ_WT + SZ_WC);
  float*  biasC = (float*)(ws + SZ_QKV + SZ_WT + SZ_WC + SZ_BC);
  bf16_t* xb    = (bf16_t*)d_out;   // d_out as scratch; dead before final GEMM

  k_transpose<<<1728, 256, 0, stream>>>(w_qkv, wT);
  k_comb<<<384, 256, 0, stream>>>(w_out, b_out, w_post, b_post, wcT, bc);
  k_bias<<<64, 256, 0, stream>>>(pos, biasC);
  k_convroll<<<(M_TOT * 48 + 255) / 256, 256, 0, stream>>>(x, xb);
  // qkv = xb @ w_qkv^T-laid-out   [50176 x 1152] bf16
  k_gemm<0><<<dim3(9, 392), 256, 0, stream>>>(xb, wT, qkv, nullptr, 1152, DIMK, DIMK);
  // attention in place (q slot)
  k_attn<<<3072, 256, 0, stream>>>(biasC, qkv);
  // out = roll^{-1}( attn @ wcomb + bcomb )   [50176 x 384] fp32
  k_gemm<1><<<dim3(3, 392), 256, 0, stream>>>(qkv, wcT, out, bc, 384, DIMK, 1152);
}

// Round 5
// 309.486 us; speedup vs baseline: 1.0420x; 1.0420x over previous
//
#include <hip/hip_runtime.h>
#include <hip/hip_bf16.h>
#include <stdint.h>

typedef __bf16 bf16_t;
typedef bf16_t bf16x8 __attribute__((ext_vector_type(8)));
typedef bf16_t bf16x4 __attribute__((ext_vector_type(4)));
typedef float f32x4 __attribute__((ext_vector_type(4)));

#define BATCH 16
#define HH    56
#define DIMK  384
#define M_TOT (BATCH*HH*HH)   // 50176
#define SCALE 0.17677669529663687f

__device__ __forceinline__ void async_load16(const bf16_t* g, const bf16_t* l) {
  __builtin_amdgcn_global_load_lds((const __attribute__((address_space(1))) void*)g,
                                   (__attribute__((address_space(3))) void*)l,
                                   16, 0, 0);
}

// DPP rotate within 16-lane row (VALU pipe — keeps softmax off the LDS pipe)
template<int CTRL>
__device__ __forceinline__ float dpp_ror(float x) {
  return __int_as_float(__builtin_amdgcn_mov_dpp(__float_as_int(x), CTRL, 0xf, 0xf, false));
}
__device__ __forceinline__ float rowmax16(float v) {
  v = fmaxf(v, dpp_ror<0x121>(v));  // row_ror:1
  v = fmaxf(v, dpp_ror<0x122>(v));  // row_ror:2
  v = fmaxf(v, dpp_ror<0x124>(v));  // row_ror:4
  v = fmaxf(v, dpp_ror<0x128>(v));  // row_ror:8
  return v;
}
__device__ __forceinline__ float rowsum16(float v) {
  v += dpp_ror<0x121>(v);
  v += dpp_ror<0x122>(v);
  v += dpp_ror<0x124>(v);
  v += dpp_ror<0x128>(v);
  return v;
}

// ---------------------------------------------------------------------------
__global__ void k_zero(float* __restrict__ p, int n) {
  int i = blockIdx.x * 256 + threadIdx.x;
  if (i < n) p[i] = 0.f;
}

// transpose w_qkv [384][1152] fp32 -> wT [1152][384] bf16
__global__ void k_transpose(const float* __restrict__ w, bf16_t* __restrict__ wT) {
  int idx = blockIdx.x * 256 + threadIdx.x;
  if (idx >= 1152 * 384) return;
  int n = idx / 384, k = idx - n * 384;
  wT[idx] = (bf16_t)w[k * 1152 + n];
}

// wcombT[n][k] = sum_j w_out[k][j] * w_post[j][n]; bcomb[n] = b_out@w_post + b_post
__global__ void k_comb(const float* __restrict__ w_out, const float* __restrict__ b_out,
                       const float* __restrict__ w_post, const float* __restrict__ b_post,
                       bf16_t* __restrict__ wcombT, float* __restrict__ bcomb) {
  __shared__ float col[384];
  const int n = blockIdx.x, t = threadIdx.x;
  for (int j = t; j < 384; j += 256) col[j] = w_post[j * 384 + n];
  __syncthreads();
  for (int k = t; k < 384; k += 256) {
    float acc = 0.f;
    for (int j = 0; j < 384; ++j) acc += w_out[k * 384 + j] * col[j];
    wcombT[n * 384 + k] = (bf16_t)acc;
  }
  if (t == 0) {
    float acc = b_post[n];
    for (int j = 0; j < 384; ++j) acc += b_out[j] * col[j];
    bcomb[n] = acc;
  }
}

// bias/mask init table in MFMA C-layout, pre-divided by SCALE.
// layout: [cls 0..3][tile=mt*4+nt][lane][reg] fp32  (64 KB)
__global__ void k_bias(const float* __restrict__ pos, float* __restrict__ biasC) {
  int idx = blockIdx.x * 256 + threadIdx.x;
  if (idx >= 4 * 16 * 64 * 4) return;
  int reg = idx & 3, lane = (idx >> 2) & 63, tile = (idx >> 8) & 15, cls = idx >> 12;
  int mt = tile >> 2, nt = tile & 3, lc = lane & 15, quad = lane >> 4;
  int m = mt * 16 + quad * 4 + reg, n = nt * 16 + lc;
  float v = -1e32f;
  if (m < 49 && n < 49) {
    int ty = m / 7, tx = m % 7, jy = n / 7, jx = n % 7;
    bool dead = ((cls & 1) && ((m >= 28) != (n >= 28))) ||
                ((cls & 2) && ((tx >= 4) != (jx >= 4)));
    v = dead ? -1e32f : pos[(jy - ty + 6) * 13 + (jx - tx + 6)] * (1.0f / SCALE);
  }
  biasC[idx] = v;
}

// x fp32 -> bf16 with roll(-3,-3) fused.  xb lives in d_out (dead scratch).
// 8 elems/thread: 2x f32x4 load -> 1x bf16x8 (16B) store.
__global__ void k_convroll(const float* __restrict__ x, bf16_t* __restrict__ xb) {
  int idx = blockIdx.x * 256 + threadIdx.x;
  if (idx >= M_TOT * 48) return;
  int row = idx / 48, c = idx - row * 48;
  int bb = row / 3136, rem = row - bb * 3136, i = rem / 56, j = rem - i * 56;
  int si = i + 3; if (si >= 56) si -= 56;
  int sj = j + 3; if (sj >= 56) sj -= 56;
  const float* src = x + ((size_t)(bb * 3136 + si * 56 + sj)) * 384 + c * 8;
  f32x4 v0 = *(const f32x4*)src;
  f32x4 v1 = *(const f32x4*)(src + 4);
  bf16x8 o;
#pragma unroll
  for (int u = 0; u < 4; ++u) { o[u] = (bf16_t)v0[u]; o[4 + u] = (bf16_t)v1[u]; }
  *(bf16x8*)(xb + (size_t)row * 384 + c * 8) = o;
}

// ---------------------------------------------------------------------------
// GEMM body: C[M x N] = A[M x K(lda)] * B^T[N x K], 128x128 tile, BK=64,
// async global->LDS staging, depth-1 prefetch double-buffer (round-3 proven
// structure: 648 TF = 2-phase structural ceiling; counted-vmcnt BK=32 variant
// REGRESSED in round 4 — T4 needs full 8-phase interleave to pay, per m196).
// LDS bank-conflict fix (T2 via m173): LDS linear, global source chunk
// permuted kc ^= (row&7), fragment reads apply the same XOR.
// XCD-chunk bijective swizzle (T1). MODE 1: fp32 C + roll(+3,+3) + bias.
template<int MODE>
__device__ __forceinline__
void gemm_body(const bf16_t* __restrict__ A, const bf16_t* __restrict__ B,
               void* __restrict__ Cv, const float* __restrict__ bias,
               int Ndim, int Kdim, int lda) {
  __shared__ __align__(16) bf16_t As[2][128 * 64];
  __shared__ __align__(16) bf16_t Bs[2][128 * 64];
  const int tid  = threadIdx.x;
  const int wave = tid >> 6;
  const int lane = tid & 63;
  const int wr = wave >> 1, wc = wave & 1;

  const int gx   = gridDim.x;
  const int nwg  = gx * gridDim.y;
  const int flat = blockIdx.y * gx + blockIdx.x;
  const int qch  = nwg >> 3;                      // tiles per XCD (nwg % 8 == 0)
  const int nf   = (flat & 7) * qch + (flat >> 3);
  const int bx   = nf % gx;
  const int by   = nf / gx;

  const int row0 = by * 128;
  const int col0 = bx * 128;

  // staging map: 1024 16B-chunks per tile (128 rows x 8 chunks), 4 rounds.
  // LDS slot (r, kc) receives GLOBAL chunk (r, kc ^ (r&7)).
  const bf16_t* aptr[4];
  const bf16_t* bptr[4];
  int dst[4];
#pragma unroll
  for (int c = 0; c < 4; ++c) {
    int linear = c * 256 + tid;
    int r  = linear >> 3;
    int kc = linear & 7;
    int gk = kc ^ (r & 7);
    dst[c] = linear * 8;                      // element offset in LDS
    aptr[c] = A + (size_t)(row0 + r) * lda + gk * 8;
    bptr[c] = B + (size_t)(col0 + r) * Kdim + gk * 8;
  }

  f32x4 acc[4][4] = {};
  const int lr = lane >> 4;
  const int lc = lane & 15;
  // fragment read offsets: row stride 64 elem (128B); chunk = kh*4+lr,
  // swizzled chunk = chunk ^ (row&7); row&7 == lc&7 here.
  unsigned aoff[4][2], boff[4][2];
#pragma unroll
  for (int mi = 0; mi < 4; ++mi)
#pragma unroll
    for (int kh = 0; kh < 2; ++kh) {
      int arow = wr * 64 + mi * 16 + lc;
      int brow = wc * 64 + mi * 16 + lc;
      int sc   = (kh * 4 + lr) ^ (lc & 7);
      aoff[mi][kh] = (unsigned)(arow * 64 + sc * 8);
      boff[mi][kh] = (unsigned)(brow * 64 + sc * 8);
    }

  const int kiters = Kdim >> 6;   // 6 (qkv) or 18 (out)

  // prologue: stage K-step 0 into buffer 0
#pragma unroll
  for (int c = 0; c < 4; ++c) {
    async_load16(aptr[c], As[0] + dst[c]);
    async_load16(bptr[c], Bs[0] + dst[c]);
  }

  for (int kt = 0; kt < kiters; ++kt) {
    const int cur = kt & 1;
    __syncthreads();   // drains prev stage (had a full compute phase to land);
                       // also orders prev iter's ds_reads before the overwrite
    if (kt + 1 < kiters) {
      const int koff = (kt + 1) * 64;
#pragma unroll
      for (int c = 0; c < 4; ++c) {
        async_load16(aptr[c] + koff, As[cur ^ 1] + dst[c]);
        async_load16(bptr[c] + koff, Bs[cur ^ 1] + dst[c]);
      }
    }
    bf16x8 af[4][2], bfr[4][2];
#pragma unroll
    for (int mi = 0; mi < 4; ++mi)
#pragma unroll
      for (int kh = 0; kh < 2; ++kh) {
        af[mi][kh]  = *(const bf16x8*)(As[cur] + aoff[mi][kh]);
        bfr[mi][kh] = *(const bf16x8*)(Bs[cur] + boff[mi][kh]);
      }
    // kh outer: dependent accumulator updates are 16 MFMAs apart
#pragma unroll
    for (int kh = 0; kh < 2; ++kh)
#pragma unroll
      for (int mi = 0; mi < 4; ++mi)
#pragma unroll
        for (int ni = 0; ni < 4; ++ni)
          acc[mi][ni] = __builtin_amdgcn_mfma_f32_16x16x32_bf16(af[mi][kh], bfr[ni][kh], acc[mi][ni], 0, 0, 0);
  }

  // Epilogue: C/D layout col=lane&15, row=quad*4+reg (verified m89/m91)
#pragma unroll
  for (int mi = 0; mi < 4; ++mi) {
#pragma unroll
    for (int rr = 0; rr < 4; ++rr) {
      int grow = row0 + wr * 64 + mi * 16 + lr * 4 + rr;
      size_t orow;
      if (MODE == 1) {
        int bb  = grow / 3136;
        int rem = grow - bb * 3136;
        int i = rem / 56;
        int j = rem - i * 56;
        int si = i + 3; if (si >= 56) si -= 56;
        int sj = j + 3; if (sj >= 56) sj -= 56;
        orow = (size_t)(bb * 3136 + si * 56 + sj);   // fused roll(+3,+3)
      } else {
        orow = (size_t)grow;
      }
#pragma unroll
      for (int ni = 0; ni < 4; ++ni) {
        int gcol = col0 + wc * 64 + ni * 16 + lc;
        float v = acc[mi][ni][rr];
        if (MODE == 1) {
          ((float*)Cv)[orow * (size_t)Ndim + gcol] = v + bias[gcol];
        } else {
          ((bf16_t*)Cv)[orow * (size_t)Ndim + gcol] = (bf16_t)v;
        }
      }
    }
  }
}

// distinct names so rocprof rows separate the two GEMMs
__global__ __launch_bounds__(256)
void k_gemm_qkv(const bf16_t* __restrict__ A, const bf16_t* __restrict__ B,
                void* __restrict__ Cv, const float* __restrict__ bias,
                int Ndim, int Kdim, int lda) {
  gemm_body<0>(A, B, Cv, bias, Ndim, Kdim, lda);
}
__global__ __launch_bounds__(256)
void k_gemm_out(const bf16_t* __restrict__ A, const bf16_t* __restrict__ B,
                void* __restrict__ Cv, const float* __restrict__ bias,
                int Ndim, int Kdim, int lda) {
  gemm_body<1>(A, B, Cv, bias, Ndim, Kdim, lda);
}

// ---------------------------------------------------------------------------
// MFMA attention: one wave per (b, head, window); 4 waves/block.
// 49 tokens padded to 64. Q/K/V fragments loaded directly from global
// (per-lane row addresses, clamp row 48 for pads). Bias+mask pre-baked in
// C-layout (biasC). Softmax reduce via DPP row_ror. P via LDS (stride 72).
// Output written in place into the q slot of qkv.
// T5: s_setprio(1) around MFMA clusters — waves here are independent (no
// barriers), the regime where m191 measured +4-7%.
__global__ __launch_bounds__(256)
void k_attn(const float* __restrict__ biasC, bf16_t* __restrict__ qkv) {
  __shared__ __align__(16) bf16_t Ps[4 * 64 * 72];   // 36864 B
  const int tid = threadIdx.x, wid = tid >> 6, lane = tid & 63;
  const int p = blockIdx.x * 4 + wid;                 // 12288 problems
  const int b = p / 768, rem = p - b * 768;
  const int head = rem >> 6, w = rem & 63;
  const int wy = w >> 3, wx = w & 7;
  const int cls = ((wy == 7) ? 1 : 0) | ((wx == 7) ? 2 : 0);
  const int lc = lane & 15, quad = lane >> 4;
  const size_t wbase = ((size_t)b * 3136 + (size_t)wy * 7 * 56 + (size_t)wx * 7) * 1152
                       + head * 32;

  // row offset (elements) for token m within this window
  auto rowoff = [&](int m) -> size_t {
    int ty = m / 7, tx = m - ty * 7;
    return wbase + (size_t)(ty * 56 + tx) * 1152;
  };

  // --- Q (A-frag) and K (B-frag) direct global loads; same rows serve both.
  bf16x8 qf[4], kf[4];
#pragma unroll
  for (int t = 0; t < 4; ++t) {
    int m = t * 16 + lc; if (m > 48) m = 48;
    const bf16_t* r = qkv + rowoff(m);
    qf[t] = *(const bf16x8*)(r + quad * 8);          // Q row m, k-chunk quad
    kf[t] = *(const bf16x8*)(r + 384 + quad * 8);    // K row m (as B-frag col)
  }

  // --- V B-frags: scalar global loads V[n=kc*32+quad*8+u][d=dt*16+lc]
  bf16x8 vf[2][2];
#pragma unroll
  for (int kc = 0; kc < 2; ++kc)
#pragma unroll
    for (int u = 0; u < 8; ++u) {
      int n = kc * 32 + quad * 8 + u; if (n > 48) n = 48;
      const bf16_t* r = qkv + rowoff(n) + 768 + lc;
      vf[kc][0][u] = r[0];
      vf[kc][1][u] = r[16];
    }

  // --- S = Q.K^T with acc initialized to (bias+mask)/SCALE
  f32x4 acc[4][4];
  const float* bp = biasC + cls * 4096 + lane * 4;
#pragma unroll
  for (int mt = 0; mt < 4; ++mt)
#pragma unroll
    for (int nt = 0; nt < 4; ++nt)
      acc[mt][nt] = *(const f32x4*)(bp + (mt * 4 + nt) * 256);
  __builtin_amdgcn_s_setprio(1);
#pragma unroll
  for (int mt = 0; mt < 4; ++mt)
#pragma unroll
    for (int nt = 0; nt < 4; ++nt)
      acc[mt][nt] = __builtin_amdgcn_mfma_f32_16x16x32_bf16(qf[mt], kf[nt], acc[mt][nt], 0, 0, 0);
  __builtin_amdgcn_s_setprio(0);

  // --- softmax over n (row m = mt*16+quad*4+reg; 16 cols/lane-row × 4 nt)
  float l[4][4];
#pragma unroll
  for (int mt = 0; mt < 4; ++mt)
#pragma unroll
    for (int reg = 0; reg < 4; ++reg) {
      float mx = fmaxf(fmaxf(acc[mt][0][reg], acc[mt][1][reg]),
                       fmaxf(acc[mt][2][reg], acc[mt][3][reg]));
      mx = rowmax16(mx);
      float s = 0.f;
#pragma unroll
      for (int nt = 0; nt < 4; ++nt) {
        float pe = __expf((acc[mt][nt][reg] - mx) * SCALE);
        acc[mt][nt][reg] = pe;
        s += pe;
      }
      l[mt][reg] = rowsum16(s);
    }

  // --- P -> LDS (C-layout scatter, stride 72: 16B-aligned rows for b128 reads)
  bf16_t* P = Ps + wid * (64 * 72);
#pragma unroll
  for (int mt = 0; mt < 4; ++mt)
#pragma unroll
    for (int nt = 0; nt < 4; ++nt)
#pragma unroll
      for (int reg = 0; reg < 4; ++reg)
        P[(mt * 16 + quad * 4 + reg) * 72 + nt * 16 + lc] = (bf16_t)acc[mt][nt][reg];

  // --- O = P.V  (A-frag = P rows from LDS; B-frag = vf)
  f32x4 oacc[4][2] = {};
#pragma unroll
  for (int mt = 0; mt < 4; ++mt) {
    bf16x8 pf0 = *(const bf16x8*)(P + (mt * 16 + lc) * 72 + quad * 8);
    bf16x8 pf1 = *(const bf16x8*)(P + (mt * 16 + lc) * 72 + 32 + quad * 8);
    __builtin_amdgcn_s_setprio(1);
#pragma unroll
    for (int dt = 0; dt < 2; ++dt) {
      oacc[mt][dt] = __builtin_amdgcn_mfma_f32_16x16x32_bf16(pf0, vf[0][dt], oacc[mt][dt], 0, 0, 0);
      oacc[mt][dt] = __builtin_amdgcn_mfma_f32_16x16x32_bf16(pf1, vf[1][dt], oacc[mt][dt], 0, 0, 0);
    }
    __builtin_amdgcn_s_setprio(0);
  }

  // --- write O into q slot (rows m<49), folding 1/l
#pragma unroll
  for (int mt = 0; mt < 4; ++mt)
#pragma unroll
    for (int reg = 0; reg < 4; ++reg) {
      int m = mt * 16 + quad * 4 + reg;
      if (m < 49) {
        float rl = __builtin_amdgcn_rcpf(l[mt][reg]);
        bf16_t* r = qkv + rowoff(m);
        r[lc]      = (bf16_t)(oacc[mt][0][reg] * rl);
        r[16 + lc] = (bf16_t)(oacc[mt][1][reg] * rl);
      }
    }
}

// ---------------------------------------------------------------------------
extern "C" void kernel_launch(void* const* d_in, const int* in_sizes, int n_in,
                              void* d_out, int out_size, void* d_ws, size_t ws_size,
                              hipStream_t stream) {
  const float* x      = (const float*)d_in[0];
  const float* w_qkv  = (const float*)d_in[1];
  const float* pos    = (const float*)d_in[2];
  const float* w_out  = (const float*)d_in[3];
  const float* b_out  = (const float*)d_in[4];
  const float* w_post = (const float*)d_in[5];
  const float* b_post = (const float*)d_in[6];
  float* out = (float*)d_out;

  const size_t SZ_QKV  = (size_t)M_TOT * 1152 * 2;   // 115.6 MB
  const size_t SZ_WT   = (size_t)1152 * 384 * 2;
  const size_t SZ_WC   = (size_t)384 * 384 * 2;
  const size_t SZ_BC   = 384 * 4;
  const size_t SZ_BIAS = (size_t)4 * 16 * 64 * 4 * 4;  // 64 KB
  const size_t NEEDED  = SZ_QKV + SZ_WT + SZ_WC + SZ_BC + SZ_BIAS;

  if (ws_size < NEEDED) {
    k_zero<<<(out_size + 255) / 256, 256, 0, stream>>>(out, out_size);
    return;
  }

  char* ws = (char*)d_ws;
  bf16_t* qkv   = (bf16_t*)ws;
  bf16_t* wT    = (bf16_t*)(ws + SZ_QKV);
  bf16_t* wcT   = (bf16_t*)(ws + SZ_QKV + SZ_WT);
  float*  bc    = (float*)(ws + SZ_QKV + SZ_WT + SZ_WC);
  float*  biasC = (float*)(ws + SZ_QKV + SZ_WT + SZ_WC + SZ_BC);
  bf16_t* xb    = (bf16_t*)d_out;   // d_out as scratch; dead before final GEMM

  k_transpose<<<1728, 256, 0, stream>>>(w_qkv, wT);
  k_comb<<<384, 256, 0, stream>>>(w_out, b_out, w_post, b_post, wcT, bc);
  k_bias<<<64, 256, 0, stream>>>(pos, biasC);
  k_convroll<<<(M_TOT * 48 + 255) / 256, 256, 0, stream>>>(x, xb);
  // qkv = xb @ w_qkv^T-laid-out   [50176 x 1152] bf16
  k_gemm_qkv<<<dim3(9, 392), 256, 0, stream>>>(xb, wT, qkv, nullptr, 1152, DIMK, DIMK);
  // attention in place (q slot)
  k_attn<<<3072, 256, 0, stream>>>(biasC, qkv);
  // out = roll^{-1}( attn @ wcomb + bcomb )   [50176 x 384] fp32
  k_gemm_out<<<dim3(3, 392), 256, 0, stream>>>(qkv, wcT, out, bc, 384, DIMK, 1152);
}